// Round 7
// baseline (62.891 us; speedup 1.0000x reference)
//
#include <hip/hip_runtime.h>
#include <hip/hip_bf16.h>
#include <math.h>

#define MARGIN_F 6.0f
// phase = pr / (REL_RANGE/PI) = pr * (PI / 0.03125)
#define PHASE_SCALE 100.53096491487338f

// ---------------------------------------------------------------------------
// K1: fused prep. grid = 16 blocks (one per b), 1024 threads (16 waves).
//  - mean-pool qh[b] (64x768) -> q[768] in LDS
//  - linear 768->18 + sigmoid (one wave per relation)
//  - mixture -> phase -> sincos -> head gather -> complex rotate
// rot layout in ws: rot_re[16][256] at float offset 0, rot_im at 4096.
// ---------------------------------------------------------------------------
__global__ void k_prep(const float* __restrict__ qh, const float* __restrict__ W,
                       const float* __restrict__ brel,
                       const float* __restrict__ rel,
                       const float* __restrict__ ent, const int* __restrict__ hid,
                       float* __restrict__ rot) {
    __shared__ float q[768];
    __shared__ float sig[18];
    int b = blockIdx.x;
    int t = threadIdx.x;

    if (t < 768) {
        float s = 0.f;
        const float* base = qh + (size_t)b * 64 * 768 + t;
        #pragma unroll 8
        for (int srow = 0; srow < 64; ++srow) s += base[(size_t)srow * 768];
        q[t] = s * (1.0f / 64.0f);
    }
    __syncthreads();

    int wave = t >> 6, lane = t & 63;
    for (int r = wave; r < 18; r += 16) {
        float p = 0.f;
        for (int h = lane; h < 768; h += 64) p += q[h] * W[r * 768 + h];
        for (int off = 32; off; off >>= 1) p += __shfl_xor(p, off, 64);
        if (lane == 0) sig[r] = 1.0f / (1.0f + expf(-(p + brel[r])));
    }
    __syncthreads();

    if (t < 256) {
        int d = t;
        float pr = 0.f;
        #pragma unroll
        for (int r = 0; r < 18; ++r) pr += sig[r] * rel[r * 256 + d];
        float phase = pr * PHASE_SCALE;
        float sn, cs;
        sincosf(phase, &sn, &cs);
        int h0 = hid[b];
        float reh = ent[(size_t)h0 * 512 + d];
        float imh = ent[(size_t)h0 * 512 + 256 + d];
        rot[b * 256 + d]        = reh * cs - imh * sn;  // rot_re
        rot[4096 + b * 256 + d] = reh * sn + imh * cs;  // rot_im
    }
}

// ---------------------------------------------------------------------------
// K2: wave-per-entity-group, 8 batch-rows per wave (pair covers b=0..15).
// G=4 entity register-blocking: per group, load 4 entity rows (te/ti, 32 VGPR)
// and 8x4 results; each rot fragment (rr/ri) is loaded ONCE per b and applied
// to all 4 entities -> rot L1 traffic drops 4x (round 6 was L1-BW-bound on
// per-entity rot re-reads: 18KB/ent/wave). lane l owns dims 4l..4l+3.
// Reduction: per-entity 10-shuffle compaction; 4 chains interleave.
// ---------------------------------------------------------------------------
__global__ __launch_bounds__(256, 4) void k_dist(const float* __restrict__ ent,
                                                 const float* __restrict__ rot,
                                                 float* __restrict__ out, int E,
                                                 int chunk) {
    int lane = threadIdx.x & 63;
    int wid = blockIdx.x * 4 + (threadIdx.x >> 6);
    int bhalf = wid & 1;       // which 8 b's this wave owns
    int pair = wid >> 1;       // entity-chunk index

    const float4* rre4 = (const float4*)rot + (size_t)bhalf * 8 * 64;
    const float4* rim4 = (const float4*)(rot + 4096) + (size_t)bhalf * 8 * 64;

    // b owned by lane l (<8) after compaction: bits (l0->b2, l1->b1, l2->b0)
    int bout = bhalf * 8 + (((lane & 1) << 2) | (lane & 2) | ((lane >> 2) & 1));

    int e0 = (int)((long long)pair * chunk);
    int e1 = min(e0 + chunk, E);
    if (e0 >= e1) return;

    for (int e = e0; e < e1; e += 4) {
        float4 te[4], ti[4];
        #pragma unroll
        for (int g = 0; g < 4; ++g) {
            int ee = min(e + g, e1 - 1);  // clamp tail reads (stores guarded)
            const float4* r4 = (const float4*)(ent + (size_t)ee * 512);
            te[g] = r4[lane];
            ti[g] = r4[64 + lane];
        }

        float v[8][4];
        #pragma unroll
        for (int b = 0; b < 8; ++b) {
            float4 rr = rre4[b * 64 + lane];  // loaded once per b, used 4x
            float4 ri = rim4[b * 64 + lane];
            #pragma unroll
            for (int g = 0; g < 4; ++g) {
                float dx0 = rr.x - te[g].x, dy0 = ri.x - ti[g].x;
                float dx1 = rr.y - te[g].y, dy1 = ri.y - ti[g].y;
                float dx2 = rr.z - te[g].z, dy2 = ri.z - ti[g].z;
                float dx3 = rr.w - te[g].w, dy3 = ri.w - ti[g].w;
                float s0 = __builtin_amdgcn_sqrtf(dx0 * dx0 + dy0 * dy0);
                float s1 = __builtin_amdgcn_sqrtf(dx1 * dx1 + dy1 * dy1);
                float s2 = __builtin_amdgcn_sqrtf(dx2 * dx2 + dy2 * dy2);
                float s3 = __builtin_amdgcn_sqrtf(dx3 * dx3 + dy3 * dy3);
                v[b][g] = (s0 + s1) + (s2 + s3);
            }
        }

        // compaction reduce per entity g: 8 values x 64 lanes -> lanes 0..7.
        // 4 independent chains; compiler interleaves them.
        #pragma unroll
        for (int g = 0; g < 4; ++g) {
            float w[8];
            #pragma unroll
            for (int b = 0; b < 8; ++b) w[b] = v[b][g];
            #pragma unroll
            for (int i = 0; i < 4; ++i) {
                float send = (lane & 1) ? w[i] : w[i + 4];
                float recv = __shfl_xor(send, 1, 64);
                w[i] = ((lane & 1) ? w[i + 4] : w[i]) + recv;
            }
            #pragma unroll
            for (int i = 0; i < 2; ++i) {
                float send = (lane & 2) ? w[i] : w[i + 2];
                float recv = __shfl_xor(send, 2, 64);
                w[i] = ((lane & 2) ? w[i + 2] : w[i]) + recv;
            }
            {
                float send = (lane & 4) ? w[0] : w[1];
                float recv = __shfl_xor(send, 4, 64);
                w[0] = ((lane & 4) ? w[1] : w[0]) + recv;
            }
            w[0] += __shfl_xor(w[0], 8, 64);
            w[0] += __shfl_xor(w[0], 16, 64);
            w[0] += __shfl_xor(w[0], 32, 64);

            if (lane < 8 && e + g < e1)
                out[(size_t)bout * E + e + g] = MARGIN_F - w[0];
        }
    }
}

extern "C" void kernel_launch(void* const* d_in, const int* in_sizes, int n_in,
                              void* d_out, int out_size, void* d_ws,
                              size_t ws_size, hipStream_t stream) {
    const float* qh   = (const float*)d_in[0];  // (16,64,768)
    const float* W    = (const float*)d_in[1];  // (18,768)
    const float* brel = (const float*)d_in[2];  // (18,)
    const float* rel  = (const float*)d_in[3];  // (18,256)
    const float* ent  = (const float*)d_in[4];  // (E,512)
    const int*   hid  = (const int*)d_in[5];    // (16,)
    float* out = (float*)d_out;

    int E = in_sizes[4] / 512;

    float* rot = (float*)d_ws;  // 2*16*256 floats = 32 KB

    k_prep<<<dim3(16), 1024, 0, stream>>>(qh, W, brel, rel, ent, hid, rot);

    const int NB = 1024;               // 4096 waves = 2048 pairs = 4/SIMD
    int npairs = NB * 4 / 2;
    int chunk = (E + npairs - 1) / npairs;  // ~22 consecutive entities/pair
    k_dist<<<dim3(NB), 256, 0, stream>>>(ent, rot, out, E, chunk);
}

// Round 8
// 57.248 us; speedup vs baseline: 1.0986x; 1.0986x over previous
//
#include <hip/hip_runtime.h>
#include <hip/hip_bf16.h>
#include <math.h>

#define MARGIN_F 6.0f
// phase = pr / (REL_RANGE/PI) = pr * (PI / 0.03125)
#define PHASE_SCALE 100.53096491487338f

// ---------------------------------------------------------------------------
// K1: fused prep. grid = 16 blocks (one per b), 1024 threads (16 waves).
//  - mean-pool qh[b] (64x768) -> q[768] in LDS
//  - linear 768->18 + sigmoid (one wave per relation)
//  - mixture -> phase -> sincos -> head gather -> complex rotate
// rot layout in ws: rot_re[16][256] at float offset 0, rot_im at 4096.
// ---------------------------------------------------------------------------
__global__ void k_prep(const float* __restrict__ qh, const float* __restrict__ W,
                       const float* __restrict__ brel,
                       const float* __restrict__ rel,
                       const float* __restrict__ ent, const int* __restrict__ hid,
                       float* __restrict__ rot) {
    __shared__ float q[768];
    __shared__ float sig[18];
    int b = blockIdx.x;
    int t = threadIdx.x;

    if (t < 768) {
        float s = 0.f;
        const float* base = qh + (size_t)b * 64 * 768 + t;
        #pragma unroll 8
        for (int srow = 0; srow < 64; ++srow) s += base[(size_t)srow * 768];
        q[t] = s * (1.0f / 64.0f);
    }
    __syncthreads();

    int wave = t >> 6, lane = t & 63;
    for (int r = wave; r < 18; r += 16) {
        float p = 0.f;
        for (int h = lane; h < 768; h += 64) p += q[h] * W[r * 768 + h];
        for (int off = 32; off; off >>= 1) p += __shfl_xor(p, off, 64);
        if (lane == 0) sig[r] = 1.0f / (1.0f + expf(-(p + brel[r])));
    }
    __syncthreads();

    if (t < 256) {
        int d = t;
        float pr = 0.f;
        #pragma unroll
        for (int r = 0; r < 18; ++r) pr += sig[r] * rel[r * 256 + d];
        float phase = pr * PHASE_SCALE;
        float sn, cs;
        sincosf(phase, &sn, &cs);
        int h0 = hid[b];
        float reh = ent[(size_t)h0 * 512 + d];
        float imh = ent[(size_t)h0 * 512 + 256 + d];
        rot[b * 256 + d]        = reh * cs - imh * sn;  // rot_re
        rot[4096 + b * 256 + d] = reh * sn + imh * cs;  // rot_im
    }
}

// ---------------------------------------------------------------------------
// K2: 4 waves/block, each wave owns 4 batch-rows (block covers b=0..15) and
// the SAME entity chunk. rot fragments per wave = 8 float4 = 32 VGPR -> fits
// the 64-VGPR tier the backend insists on, so rot is genuinely register-
// resident (rounds 3/5/7 showed bigger declared tiles get un-CSE'd into L1
// re-reads). Hot loop per entity: 2 coalesced float4 loads + 64 VALU +
// 16 sqrt + 7-shuffle compaction reduce. lane l owns dims 4l..4l+3.
// ---------------------------------------------------------------------------
__global__ __launch_bounds__(256, 4) void k_dist(const float* __restrict__ ent,
                                                 const float* __restrict__ rot,
                                                 float* __restrict__ out, int E,
                                                 int chunk) {
    int lane = threadIdx.x & 63;
    int w4 = threadIdx.x >> 6;  // which 4 b's this wave owns

    const float4* rre4 = (const float4*)rot + (size_t)w4 * 4 * 64;
    const float4* rim4 = (const float4*)(rot + 4096) + (size_t)w4 * 4 * 64;
    float4 ra[4], ia[4];
    #pragma unroll
    for (int b = 0; b < 4; ++b) {
        ra[b] = rre4[b * 64 + lane];
        ia[b] = rim4[b * 64 + lane];
    }

    // b owned by lane l (<4) after compaction: b = 2*l0 + l1
    int bout = w4 * 4 + (((lane & 1) << 1) | ((lane >> 1) & 1));

    int e0 = blockIdx.x * chunk;
    int e1 = min(e0 + chunk, E);

    for (int e = e0; e < e1; ++e) {
        const float4* r4 = (const float4*)(ent + (size_t)e * 512);
        float4 te = r4[lane];
        float4 ti = r4[64 + lane];

        float v[4];
        #pragma unroll
        for (int b = 0; b < 4; ++b) {
            float dx0 = ra[b].x - te.x, dy0 = ia[b].x - ti.x;
            float dx1 = ra[b].y - te.y, dy1 = ia[b].y - ti.y;
            float dx2 = ra[b].z - te.z, dy2 = ia[b].z - ti.z;
            float dx3 = ra[b].w - te.w, dy3 = ia[b].w - ti.w;
            float s0 = __builtin_amdgcn_sqrtf(dx0 * dx0 + dy0 * dy0);
            float s1 = __builtin_amdgcn_sqrtf(dx1 * dx1 + dy1 * dy1);
            float s2 = __builtin_amdgcn_sqrtf(dx2 * dx2 + dy2 * dy2);
            float s3 = __builtin_amdgcn_sqrtf(dx3 * dx3 + dy3 * dy3);
            v[b] = (s0 + s1) + (s2 + s3);
        }

        // compaction reduce: 4 values x 64 lanes -> 1 value on lanes 0..3
        #pragma unroll
        for (int i = 0; i < 2; ++i) {
            float send = (lane & 1) ? v[i] : v[i + 2];
            float recv = __shfl_xor(send, 1, 64);
            v[i] = ((lane & 1) ? v[i + 2] : v[i]) + recv;
        }
        {
            float send = (lane & 2) ? v[0] : v[1];
            float recv = __shfl_xor(send, 2, 64);
            v[0] = ((lane & 2) ? v[1] : v[0]) + recv;
        }
        v[0] += __shfl_xor(v[0], 4, 64);
        v[0] += __shfl_xor(v[0], 8, 64);
        v[0] += __shfl_xor(v[0], 16, 64);
        v[0] += __shfl_xor(v[0], 32, 64);

        if (lane < 4) out[(size_t)bout * E + e] = MARGIN_F - v[0];
    }
}

extern "C" void kernel_launch(void* const* d_in, const int* in_sizes, int n_in,
                              void* d_out, int out_size, void* d_ws,
                              size_t ws_size, hipStream_t stream) {
    const float* qh   = (const float*)d_in[0];  // (16,64,768)
    const float* W    = (const float*)d_in[1];  // (18,768)
    const float* brel = (const float*)d_in[2];  // (18,)
    const float* rel  = (const float*)d_in[3];  // (18,256)
    const float* ent  = (const float*)d_in[4];  // (E,512)
    const int*   hid  = (const int*)d_in[5];    // (16,)
    float* out = (float*)d_out;

    int E = in_sizes[4] / 512;

    float* rot = (float*)d_ws;  // 2*16*256 floats = 32 KB

    k_prep<<<dim3(16), 1024, 0, stream>>>(qh, W, brel, rel, ent, hid, rot);

    const int NB = 2048;  // 8192 waves = 8/SIMD (64-VGPR tier capacity)
    int chunk = (E + NB - 1) / NB;  // ~22 consecutive entities per block
    k_dist<<<dim3(NB), 256, 0, stream>>>(ent, rot, out, E, chunk);
}